// Round 1
// baseline (193.148 us; speedup 1.0000x reference)
//
#include <hip/hip_runtime.h>
#include <cstdint>
#include <cmath>

// ---------------------------------------------------------------------------
// GProjection: project B*N points into V=3 views, bilinear-sample 3 feature
// pyramids (64@56x56, 128@28x28, 256@14x14 -> 448 ch), reduce max/mean/std
// over views. Output [B,N,3+3*448] f32.
// ---------------------------------------------------------------------------

__global__ void setup_cams_kernel(const float* __restrict__ poses,
                                  const int* __restrict__ resolution,
                                  float* __restrict__ ws, int BV) {
    int t = blockIdx.x * blockDim.x + threadIdx.x;
    if (t == 0) {
        float h0 = ((float)resolution[0] - 1.0f) * 0.5f;
        float h1 = ((float)resolution[1] - 1.0f) * 0.5f;
        ws[0] = 111.5f - h0;   // c_off0
        ws[1] = 111.5f - h1;   // c_off1
        ws[2] = h0;            // half_res0
        ws[3] = h1;            // half_res1
    }
    if (t < BV) {
        const float* p = poses + (size_t)t * 5;
        const float d = 0.017453292519943295f;  // pi/180
        float theta = p[0] * d;
        float elr   = p[1] * d;
        float dist  = p[3];
        float st = sinf(theta), ct = cosf(theta);
        float se = sinf(elr),   ce = cosf(elr);
        float camy = dist * se;
        float lens = dist * ce;
        float camx = lens * ct;
        float camz = lens * st;
        // Z = camera origin direction, Y = up-ish, X = cross(Y,Z)
        float Zx = camx, Zy = camy, Zz = camz;
        float Yx = -camy * ct, Yy = lens, Yz = -camy * st;  // cos/sin(theta+pi)
        float Xx = Yy * Zz - Yz * Zy;
        float Xy = Yz * Zx - Yx * Zz;
        float Xz = Yx * Zy - Yy * Zx;
        float rx = 1.0f / sqrtf(Xx*Xx + Xy*Xy + Xz*Xz);
        float ry = 1.0f / sqrtf(Yx*Yx + Yy*Yy + Yz*Yz);
        float rz = 1.0f / sqrtf(Zx*Zx + Zy*Zy + Zz*Zz);
        float* c = ws + 4 + (size_t)t * 12;
        c[0] = Xx*rx; c[1] = Xy*rx; c[2] = Xz*rx;   // row 0
        c[3] = Yx*ry; c[4] = Yy*ry; c[5] = Yz*ry;   // row 1
        c[6] = Zx*rz; c[7] = Zy*rz; c[8] = Zz*rz;   // row 2
        c[9] = camx; c[10] = camy; c[11] = camz;    // origin
    }
}

// [C][P] -> [P][C] per slice (slice = blockIdx.z), classic LDS tile transpose
__global__ void transpose_cp_kernel(const float* __restrict__ in,
                                    float* __restrict__ out, int C, int P) {
    __shared__ float tile[32][33];
    int slice = blockIdx.z;
    const float* src = in + (size_t)slice * C * P;
    float* dst = out + (size_t)slice * C * P;
    int p0 = blockIdx.x * 32, c0 = blockIdx.y * 32;
    int tx = threadIdx.x, ty = threadIdx.y;  // 32 x 8
#pragma unroll
    for (int i = 0; i < 32; i += 8) {
        int c = c0 + ty + i, p = p0 + tx;
        if (c < C && p < P) tile[ty + i][tx] = src[(size_t)c * P + p];
    }
    __syncthreads();
#pragma unroll
    for (int i = 0; i < 32; i += 8) {
        int p = p0 + ty + i, c = c0 + tx;
        if (p < P && c < C) dst[(size_t)p * C + c] = tile[tx][ty + i];
    }
}

struct Corners {
    int p00, p10, p01, p11;
    float w00, w10, w01, w11;
};

__device__ __forceinline__ Corners mk_corners(float gx, float gy, int S) {
    // torch grid_sample, bilinear, zeros padding, align_corners=False
    float x = ((gx + 1.0f) * (float)S - 1.0f) * 0.5f;
    float y = ((gy + 1.0f) * (float)S - 1.0f) * 0.5f;
    float x0f = floorf(x), y0f = floorf(y);
    float wx1 = x - x0f, wy1 = y - y0f;
    float wx0 = 1.0f - wx1, wy0 = 1.0f - wy1;
    int x0 = (int)x0f, y0 = (int)y0f;
    int x1 = x0 + 1, y1 = y0 + 1;
    bool vx0 = (x0 >= 0) && (x0 <= S - 1);
    bool vx1 = (x1 >= 0) && (x1 <= S - 1);
    bool vy0 = (y0 >= 0) && (y0 <= S - 1);
    bool vy1 = (y1 >= 0) && (y1 <= S - 1);
    int xi0 = min(max(x0, 0), S - 1);
    int xi1 = min(max(x1, 0), S - 1);
    int yi0 = min(max(y0, 0), S - 1);
    int yi1 = min(max(y1, 0), S - 1);
    Corners c;
    c.p00 = yi0 * S + xi0;
    c.p10 = yi0 * S + xi1;
    c.p01 = yi1 * S + xi0;
    c.p11 = yi1 * S + xi1;
    c.w00 = wx0 * wy0 * ((vx0 && vy0) ? 1.0f : 0.0f);
    c.w10 = wx1 * wy0 * ((vx1 && vy0) ? 1.0f : 0.0f);
    c.w01 = wx0 * wy1 * ((vx0 && vy1) ? 1.0f : 0.0f);
    c.w11 = wx1 * wy1 * ((vx1 && vy1) ? 1.0f : 0.0f);
    return c;
}

template <bool TR>
__device__ __forceinline__ float samp(const float* __restrict__ base,
                                      const Corners& cr, int C, int P, int c) {
    if (TR) {  // channel-last [P][C]
        return cr.w00 * base[(size_t)cr.p00 * C + c]
             + cr.w10 * base[(size_t)cr.p10 * C + c]
             + cr.w01 * base[(size_t)cr.p01 * C + c]
             + cr.w11 * base[(size_t)cr.p11 * C + c];
    } else {   // channel-first [C][P]
        const float* bc = base + (size_t)c * P;
        return cr.w00 * bc[cr.p00] + cr.w10 * bc[cr.p10]
             + cr.w01 * bc[cr.p01] + cr.w11 * bc[cr.p11];
    }
}

template <bool TR>
__global__ __launch_bounds__(256) void gproj_main_kernel(
    const float* __restrict__ f0, const float* __restrict__ f1,
    const float* __restrict__ f2, const float* __restrict__ inputs,
    const float* __restrict__ cams, float* __restrict__ out, int B, int N) {
    const int wave = threadIdx.x >> 6;
    const int lane = threadIdx.x & 63;
    const int point = blockIdx.x * 4 + wave;
    if (point >= B * N) return;
    const int b = point / N;

    const float c_off0 = cams[0], c_off1 = cams[1];
    const float inv_h0 = 1.0f / cams[2], inv_h1 = 1.0f / cams[3];
    const float* cam = cams + 4;

    const float* ip = inputs + (size_t)point * 3;
    const float in0 = ip[0], in1 = ip[1], in2 = ip[2];
    const float px = in0, py = in1, pz = in2 - 0.8f;  // + MESH_POS

    // world = camera_trans_inv(pose[b,0], p) = p @ cm0 + o0
    const float* m0 = cam + (size_t)(b * 3) * 12;
    const float wx = px * m0[0] + py * m0[3] + pz * m0[6] + m0[9];
    const float wy = px * m0[1] + py * m0[4] + pz * m0[7] + m0[10];
    const float wz = px * m0[2] + py * m0[5] + pz * m0[8] + m0[11];

    float vals[3][7];

#pragma unroll
    for (int v = 0; v < 3; ++v) {
        const float* m = cam + (size_t)(b * 3 + v) * 12;
        float qx = wx - m[9], qy = wy - m[10], qz = wz - m[11];
        float Xc = m[0] * qx + m[1] * qy + m[2] * qz;
        float Yc = m[3] * qx + m[4] * qy + m[5] * qz;
        float Zc = m[6] * qx + m[7] * qy + m[8] * qz;
        float invZ = 1.0f / Zc;
        float wpix = -248.0f * (Xc * invZ) + c_off0;
        float hpix =  248.0f * (Yc * invZ) + c_off1;
        float gx = fminf(fmaxf(wpix * inv_h0, -1.0f), 1.0f);
        float gy = fminf(fmaxf(hpix * inv_h1, -1.0f), 1.0f);

        Corners cr0 = mk_corners(gx, gy, 56);
        Corners cr1 = mk_corners(gx, gy, 28);
        Corners cr2 = mk_corners(gx, gy, 14);

        int slice = v * B + b;
        const float* b0 = f0 + (size_t)slice * 64 * 3136;
        const float* b1 = f1 + (size_t)slice * 128 * 784;
        const float* b2 = f2 + (size_t)slice * 256 * 196;

        // channel g = lane + 64*k; k=0 -> feat0, k=1,2 -> feat1, k=3..6 -> feat2
        vals[v][0] = samp<TR>(b0, cr0, 64, 3136, lane);
        vals[v][1] = samp<TR>(b1, cr1, 128, 784, lane);
        vals[v][2] = samp<TR>(b1, cr1, 128, 784, lane + 64);
        vals[v][3] = samp<TR>(b2, cr2, 256, 196, lane);
        vals[v][4] = samp<TR>(b2, cr2, 256, 196, lane + 64);
        vals[v][5] = samp<TR>(b2, cr2, 256, 196, lane + 128);
        vals[v][6] = samp<TR>(b2, cr2, 256, 196, lane + 192);
    }

    float* op = out + (size_t)point * 1347;
    if (lane < 3) op[lane] = ip[lane];
#pragma unroll
    for (int k = 0; k < 7; ++k) {
        float a = vals[0][k], bv = vals[1][k], cv = vals[2][k];
        float mx = fmaxf(a, fmaxf(bv, cv));
        float mean = (a + bv + cv) * (1.0f / 3.0f);
        float da = a - mean, db = bv - mean, dc = cv - mean;
        float sd = sqrtf((da * da + db * db + dc * dc) * 0.5f);  // ddof=1
        int g = lane + 64 * k;
        op[3 + g] = mx;
        op[451 + g] = mean;
        op[899 + g] = sd;
    }
}

extern "C" void kernel_launch(void* const* d_in, const int* in_sizes, int n_in,
                              void* d_out, int out_size, void* d_ws, size_t ws_size,
                              hipStream_t stream) {
    const float* feat0 = (const float*)d_in[0];
    const float* feat1 = (const float*)d_in[1];
    const float* feat2 = (const float*)d_in[2];
    const float* inputs = (const float*)d_in[3];
    const float* poses = (const float*)d_in[4];
    const int* resolution = (const int*)d_in[5];
    float* out = (float*)d_out;
    float* ws = (float*)d_ws;

    const int V = 3;
    const int B = in_sizes[4] / (V * 5);
    const int N = in_sizes[3] / (B * 3);
    const int BV = B * V;

    setup_cams_kernel<<<1, 64, 0, stream>>>(poses, resolution, ws, BV);

    const size_t cams_elems = 512;  // params(4) + 24*12, padded for alignment
    const size_t t0_elems = (size_t)BV * 64 * 3136;
    const size_t t1_elems = (size_t)BV * 128 * 784;
    const size_t t2_elems = (size_t)BV * 256 * 196;
    const size_t need = (cams_elems + t0_elems + t1_elems + t2_elems) * sizeof(float);

    const int total = B * N;
    const int nblocks = (total + 3) / 4;  // 4 waves (points) per 256-thread block

    if (ws_size >= need) {
        float* t0 = ws + cams_elems;
        float* t1 = t0 + t0_elems;
        float* t2 = t1 + t1_elems;
        dim3 blk(32, 8);
        transpose_cp_kernel<<<dim3((3136 + 31) / 32, 64 / 32, BV), blk, 0, stream>>>(feat0, t0, 64, 3136);
        transpose_cp_kernel<<<dim3((784 + 31) / 32, 128 / 32, BV), blk, 0, stream>>>(feat1, t1, 128, 784);
        transpose_cp_kernel<<<dim3((196 + 31) / 32, 256 / 32, BV), blk, 0, stream>>>(feat2, t2, 256, 196);
        gproj_main_kernel<true><<<nblocks, 256, 0, stream>>>(t0, t1, t2, inputs, ws, out, B, N);
    } else {
        gproj_main_kernel<false><<<nblocks, 256, 0, stream>>>(feat0, feat1, feat2, inputs, ws, out, B, N);
    }
}